// Round 10
// baseline (67.009 us; speedup 1.0000x reference)
//
#include <hip/hip_runtime.h>
#include <hip/hip_bf16.h>

#define NB 4
#define CCH 256
#define NN 4096
#define QT 256
#define KSPLIT 8
#define MRANGE (NN / KSPLIT)
#define MTILE 64
#define NTILES (MRANGE / MTILE)
#define VPAD 8

// sqrt(log2(e)/16): fold softmax scale + exp2 conversion into x symmetrically
#define SQRTK 0.30028060f

typedef __attribute__((ext_vector_type(8))) short short8;
typedef __attribute__((ext_vector_type(16))) float f32x16;
typedef __attribute__((ext_vector_type(4))) int i32x4;

__device__ inline ushort f2bf(float f) {
    uint u = __float_as_uint(f);
    uint r = (u + 0x7fffu + ((u >> 16) & 1u)) >> 16;
    return (ushort)r;
}

__device__ inline float dev_exp2(float x) {
#if __has_builtin(__builtin_amdgcn_exp2f)
    return __builtin_amdgcn_exp2f(x);
#else
    return exp2f(x);
#endif
}

__device__ inline void gl_lds16(const void* g, void* l) {
    __builtin_amdgcn_global_load_lds(
        (const __attribute__((address_space(1))) unsigned int*)g,
        (__attribute__((address_space(3))) unsigned int*)l, 16, 0, 0);
}

// ---------------- Kernel E: W fp32 -> bf16 ----------------
__global__ void wconv_k(const float* __restrict__ W, ushort* __restrict__ Wb) {
    int i = blockIdx.x * 256 + threadIdx.x;  // 16384 float4
    float4 v = reinterpret_cast<const float4*>(W)[i];
    ushort4 r;
    r.x = f2bf(v.x); r.y = f2bf(v.y); r.z = f2bf(v.z); r.w = f2bf(v.w);
    reinterpret_cast<ushort4*>(Wb)[i] = r;
}

// ---------------- Kernel B': fused transpose+linear
// Per wg: 64 n-rows x full C. Build bf16 [n][c] tile in LDS from inp
// [B][C][N] (transpose via f32 LDS tile, 4 c-blocks serially), then the
// R9-proven MFMA GEMM vs Wb (global, L2-hot). Skips inpT entirely
// (saves 8MB write + 8MB read vs separate transp_k + linear_k).
__global__ __launch_bounds__(256) void fusedlin_k(const float* __restrict__ inp,
                                                  const ushort* __restrict__ Wb,
                                                  const float* __restrict__ bias,
                                                  ushort* __restrict__ xs) {
    int wg = blockIdx.x;                 // 256: b(2) | nt(6)
    int b = wg >> 6, nt = wg & 63;
    int t = threadIdx.x, l = t & 63, w = t >> 6;
    __shared__ float ftile[64 * 67];
    __shared__ ushort xtile[64][260];    // row stride 520B: 2-way conflicts only

    for (int cblk = 0; cblk < 4; cblk++) {
        const float* src = inp + ((size_t)(b * CCH + cblk * 64)) * NN + nt * 64;
#pragma unroll
        for (int p = 0; p < 4; p++) {
            int ci = p * 256 + t;        // 0..1023
            int c = ci >> 4, n4 = ci & 15;
            float4 v = *reinterpret_cast<const float4*>(src + (size_t)c * NN + n4 * 4);
            float* d = &ftile[c * 67 + n4 * 4];
            d[0] = v.x; d[1] = v.y; d[2] = v.z; d[3] = v.w;
        }
        __syncthreads();
#pragma unroll
        for (int p = 0; p < 2; p++) {
            int u = p * 256 + t;         // 0..511
            int n = u >> 3, cc = u & 7;
            ushort tmp[8];
#pragma unroll
            for (int j = 0; j < 8; j++) tmp[j] = f2bf(ftile[(cc * 8 + j) * 67 + n]);
            uint4 o;
            o.x = (uint)tmp[0] | ((uint)tmp[1] << 16);
            o.y = (uint)tmp[2] | ((uint)tmp[3] << 16);
            o.z = (uint)tmp[4] | ((uint)tmp[5] << 16);
            o.w = (uint)tmp[6] | ((uint)tmp[7] << 16);
            *reinterpret_cast<uint4*>(&xtile[n][cblk * 64 + cc * 8]) = o;
        }
        __syncthreads();
    }

    int nb = (w & 1) * 32;
    int obase = (w >> 1) * 128;
    const ushort* wrow = Wb + ((size_t)(obase + (l & 31))) * CCH + ((l >> 5) * 8);
    f32x16 acc[4];
#pragma unroll
    for (int os = 0; os < 4; os++)
#pragma unroll
        for (int r = 0; r < 16; r++) acc[os][r] = 0.f;

    const char* arow = (const char*)&xtile[nb + (l & 31)][0] + (l >> 5) * 16;
#pragma unroll
    for (int ch = 0; ch < 16; ch++) {
        short8 a = *reinterpret_cast<const short8*>(arow + ch * 32);
#pragma unroll
        for (int os = 0; os < 4; os++) {
            short8 bb = *reinterpret_cast<const short8*>(wrow + (size_t)os * 32 * CCH + ch * 16);
            acc[os] = __builtin_amdgcn_mfma_f32_32x32x16_bf16(a, bb, acc[os], 0, 0, 0);
        }
    }
#pragma unroll
    for (int os = 0; os < 4; os++) {
        int oc = obase + os * 32 + (l & 31);
        float bv = bias[oc];
#pragma unroll
        for (int r = 0; r < 16; r++) {
            int row = (r & 3) + 8 * (r >> 2) + 4 * (l >> 5);
            float v = (acc[os][r] + bv) * SQRTK;
            xs[((size_t)(b * NN + nt * 64 + nb + row)) * CCH + oc] = f2bf(v);
        }
    }
}

// ---------------- Kernel C: flash attention, PV+denominator via MFMA, FAT waves
// Each wave computes 64 q-rows (qf0/qf1): one K-fragment LDS read feeds TWO
// QK MFMAs -> K LDS-read traffic (the R9 dominant pipe, ~52% busy) halves.
// ~225 total regs: __launch_bounds__(256,2) permits 256 VGPR (2 waves/SIMD,
// 8 waves/CU with 2 wgs/CU). Swapped QK^T (q on lanes, m in regs); V' =
// [fx,fy,1,0] pre-permuted in LDS (bits 2<->3 of m&15) so P packs in reg
// order: 16 cvt_pk, no shuffles. R7 dbuf shell, no tile-loop unroll.
__global__ __launch_bounds__(256, 2) void attn_k(const ushort* __restrict__ xs,
                                                 const float* __restrict__ flow,
                                                 float* __restrict__ part) {
    int wg = blockIdx.x;                 // 512: b(2) | qt(4) | ks(3)
    int b = wg >> 7;
    int qt = (wg >> 3) & 15;
    int ks = wg & 7;
    int t = threadIdx.x, l = t & 63, w = t >> 6;   // w = 0..3
    const ushort* xb = xs + (size_t)b * NN * CCH;
    int qbase = qt * QT + w * 64;
    int mstart = ks * MRANGE;

    __shared__ ushort kt[2][MTILE * 256];        // 2 x 32KB K-tiles
    __shared__ ushort vlds[4][MRANGE + VPAD];    // perm-ordered V': fx|fy|1|0

    // build V': thread t handles m = t*2, t*2+1 of this wg's 512-m slice
    {
        int m0 = t * 2;
        float2 fx2 = *reinterpret_cast<const float2*>(flow + (size_t)b * 2 * NN + mstart + m0);
        float2 fy2 = *reinterpret_cast<const float2*>(flow + (size_t)b * 2 * NN + NN + mstart + m0);
        float fxv[2] = {fx2.x, fx2.y};
        float fyv[2] = {fy2.x, fy2.y};
#pragma unroll
        for (int i = 0; i < 2; i++) {
            int m = m0 + i, ml = m & 15;
            int pos = (m & ~15) | (ml & 3) | ((ml & 4) << 1) | ((ml & 8) >> 1);
            vlds[0][pos] = f2bf(fxv[i]);
            vlds[1][pos] = f2bf(fyv[i]);
            vlds[2][pos] = 0x3F80;       // bf16 1.0
            vlds[3][pos] = 0;
        }
    }

    // Q fragments: 64 q-rows x 256 c per wave (two 32-row halves)
    short8 qf0[16], qf1[16];
    const ushort* qrow0 = xb + ((size_t)(qbase + (l & 31))) * CCH + (l >> 5) * 8;
    const ushort* qrow1 = qrow0 + (size_t)32 * CCH;
#pragma unroll
    for (int ch = 0; ch < 16; ch++) {
        qf0[ch] = *reinterpret_cast<const short8*>(qrow0 + ch * 16);
        qf1[ch] = *reinterpret_cast<const short8*>(qrow1 + ch * 16);
    }

    f32x16 pv0, pv1;                     // persistent: cols {X,Y,S,0...}
#pragma unroll
    for (int r = 0; r < 16; r++) { pv0[r] = 0.f; pv1[r] = 0.f; }

    // staging: 32 chunks of 1KB across 4 waves; source XOR-swizzled (16 slots)
    auto stage = [&](int buf, int tile) {
        int mb = mstart + tile * MTILE;
        const char* src = (const char*)(xb + (size_t)mb * CCH);
#pragma unroll
        for (int p = 0; p < 8; p++) {
            int chunk = w * 8 + p;
            int lin = chunk * 1024 + l * 16;
            int row = lin >> 9;
            int cb = lin & 511;
            int gsw = cb ^ ((row & 15) << 4);
            gl_lds16(src + (size_t)row * 512 + gsw, &kt[buf][chunk * 512]);
        }
    };

    int c_sel = (l & 31) < 3 ? (l & 31) : 3;
    stage(0, 0);
    __syncthreads();
    int cur = 0;
    for (int tile = 0; tile < NTILES; tile++) {
        if (tile + 1 < NTILES) stage(cur ^ 1, tile + 1);
#pragma unroll
        for (int ms = 0; ms < 2; ms++) {
            f32x16 S0, S1;
#pragma unroll
            for (int r = 0; r < 16; r++) { S0[r] = 0.f; S1[r] = 0.f; }
            const char* base = (const char*)&kt[cur][(ms * 32 + (l & 31)) * 256];
            int swz = (l & 15) << 4;
#pragma unroll
            for (int ch = 0; ch < 16; ch++) {
                int cbyte = (ch * 32 + ((l >> 5) * 16)) ^ swz;
                short8 kf = *reinterpret_cast<const short8*>(base + cbyte);
                S0 = __builtin_amdgcn_mfma_f32_32x32x16_bf16(kf, qf0[ch], S0, 0, 0, 0);
                S1 = __builtin_amdgcn_mfma_f32_32x32x16_bf16(kf, qf1[ch], S1, 0, 0, 0);
            }
#pragma unroll
            for (int r = 0; r < 16; r++) { S0[r] = dev_exp2(S0[r]); S1[r] = dev_exp2(S1[r]); }
            uint wa[8], wb2[8];
#pragma unroll
            for (int p = 0; p < 8; p++) {
                asm("v_cvt_pk_bf16_f32 %0, %1, %2" : "=v"(wa[p]) : "v"(S0[2 * p]), "v"(S0[2 * p + 1]));
                asm("v_cvt_pk_bf16_f32 %0, %1, %2" : "=v"(wb2[p]) : "v"(S1[2 * p]), "v"(S1[2 * p + 1]));
            }
            i32x4 a0 = {(int)wa[0], (int)wa[1], (int)wa[2], (int)wa[3]};
            i32x4 a1 = {(int)wa[4], (int)wa[5], (int)wa[6], (int)wa[7]};
            i32x4 b0 = {(int)wb2[0], (int)wb2[1], (int)wb2[2], (int)wb2[3]};
            i32x4 b1 = {(int)wb2[4], (int)wb2[5], (int)wb2[6], (int)wb2[7]};
            short8 pa00 = __builtin_bit_cast(short8, a0);
            short8 pa01 = __builtin_bit_cast(short8, a1);
            short8 pa10 = __builtin_bit_cast(short8, b0);
            short8 pa11 = __builtin_bit_cast(short8, b1);
            int mloc = tile * MTILE + ms * 32;
            const ushort* vb = &vlds[c_sel][mloc + (l >> 5) * 8];
            short8 v0 = *reinterpret_cast<const short8*>(vb);
            short8 v1 = *reinterpret_cast<const short8*>(vb + 16);
            pv0 = __builtin_amdgcn_mfma_f32_32x32x16_bf16(pa00, v0, pv0, 0, 0, 0);
            pv0 = __builtin_amdgcn_mfma_f32_32x32x16_bf16(pa01, v1, pv0, 0, 0, 0);
            pv1 = __builtin_amdgcn_mfma_f32_32x32x16_bf16(pa10, v0, pv1, 0, 0, 0);
            pv1 = __builtin_amdgcn_mfma_f32_32x32x16_bf16(pa11, v1, pv1, 0, 0, 0);
        }
        __syncthreads();
        cur ^= 1;
    }

    // epilogue: lane col 0 holds X, 1 holds Y, 2 holds S (16 q each)
    int c = l & 31;
    if (c < 3) {
        float* pb = part + ((size_t)(b * KSPLIT + ks)) * 3 * NN;
        int off = ((c + 1) % 3) * NN;    // c2->S@0, c0->X@NN, c1->Y@2NN
#pragma unroll
        for (int r = 0; r < 16; r++) {
            int row = (r & 3) + 8 * (r >> 2) + 4 * (l >> 5);
            pb[off + qbase + row] = pv0[r];
            pb[off + qbase + 32 + row] = pv1[r];
        }
    }
}

// ---------------- Kernel D: combine k-split partials, divide, write output
__global__ void finalize_k(const float* __restrict__ part, float* __restrict__ out) {
    int i = blockIdx.x * 256 + threadIdx.x;  // 16384
    int b = i >> 12, n = i & 4095;
    float s = 0.f, x = 0.f, y = 0.f;
#pragma unroll
    for (int ks = 0; ks < KSPLIT; ks++) {
        const float* p = part + ((size_t)(b * KSPLIT + ks)) * 3 * NN;
        s += p[n];
        x += p[NN + n];
        y += p[2 * NN + n];
    }
    out[(size_t)b * 2 * NN + n] = x / s;
    out[(size_t)b * 2 * NN + NN + n] = y / s;
}

extern "C" void kernel_launch(void* const* d_in, const int* in_sizes, int n_in,
                              void* d_out, int out_size, void* d_ws, size_t ws_size,
                              hipStream_t stream) {
    const float* inp  = (const float*)d_in[0];
    // d_in[1] = inter_mask: unused by the reference
    const float* flow = (const float*)d_in[2];
    const float* W    = (const float*)d_in[3];
    const float* bias = (const float*)d_in[4];
    float* out = (float*)d_out;

    char* ws = (char*)d_ws;
    ushort* xs   = (ushort*)(ws);                  // 8 MB  x_scaled bf16 [B][N][C]
    float*  part = (float*)(ws + 8388608);         // 1.5MB partials [B][KS][3][N]
    ushort* Wb   = (ushort*)(ws + 16777216);       // 128KB W bf16 [C][C]

    wconv_k<<<64, 256, 0, stream>>>(W, Wb);
    fusedlin_k<<<256, 256, 0, stream>>>(inp, Wb, bias, xs);
    attn_k<<<512, 256, 0, stream>>>(xs, flow, part);
    finalize_k<<<64, 256, 0, stream>>>(part, out);
}